// Round 9
// baseline (176.541 us; speedup 1.0000x reference)
//
#include <hip/hip_runtime.h>

// W4A16 GEMM, M=N=K=4096, GROUP=128, zp=8.
// Inputs (harness presents fp16 as f32): x f32[M,K], scale f32[32,N],
// q_weight int32[K,N] (0..15). Output f32[M,N].
//
// Fast path (ws >= 64MB):
//   P0 convert_x: x f32 -> Xh fp16 [M,K]
//   P1 dequant_transpose: q -> Wt fp16 [N,K]
//   P2 gemm_2b: 128x256 tile, BK=32, 8 waves (64x64/wave), LDS 48KB ->
//      2 BLOCKS/CU (the r5-r8 plateau was 1-block/CU lockstep: LDS pipe and
//      MFMA pipe alternated; a second independent block fills the idle pipe).
//      Per block: r5-proven counted-vmcnt 2-barrier loop, read-side XOR
//      swizzle, XCD swizzle. grid 512 = 2 x 256 CUs exactly.
// Fallback (ws >= 32MB): proven round-3 reg-staged 128x128 GEMM.

#define MDIM 4096
#define NDIM 4096
#define KDIM 4096

typedef __attribute__((ext_vector_type(8))) _Float16 f16x8;
typedef __attribute__((ext_vector_type(4))) float    f32x4;
typedef __attribute__((ext_vector_type(4))) int      i32x4;

__device__ __forceinline__ unsigned short f2h(float f) {
    union { _Float16 h; unsigned short u; } v;
    v.h = (_Float16)f;  // RNE
    return v.u;
}

// ---------------- diagnostic fallback ----------------
__global__ void zero_fill(float* __restrict__ out, int n) {
    int i = blockIdx.x * blockDim.x + threadIdx.x;
    if (i < n) out[i] = 0.f;
}

// ---------------- P0: x f32 -> fp16 ----------------
__global__ void convert_x(const float* __restrict__ x,
                          unsigned short* __restrict__ xh, int n8) {
    int i = blockIdx.x * blockDim.x + threadIdx.x;
    const int stride = gridDim.x * blockDim.x;
    for (; i < n8; i += stride) {
        const float4 a = ((const float4*)x)[(size_t)i * 2];
        const float4 b = ((const float4*)x)[(size_t)i * 2 + 1];
        f16x8 r;
        r[0] = (_Float16)a.x; r[1] = (_Float16)a.y;
        r[2] = (_Float16)a.z; r[3] = (_Float16)a.w;
        r[4] = (_Float16)b.x; r[5] = (_Float16)b.y;
        r[6] = (_Float16)b.z; r[7] = (_Float16)b.w;
        *(f16x8*)&xh[(size_t)i * 8] = r;
    }
}

// ---------------- P1: dequant + transpose ----------------
__global__ void dequant_transpose(const int* __restrict__ q,
                                  const float* __restrict__ scale,
                                  unsigned short* __restrict__ wt) {
    __shared__ unsigned short lds[64][65];
    const int t  = threadIdx.x;
    const int k0 = blockIdx.x * 64;
    const int n0 = blockIdx.y * 64;
    const int g  = k0 >> 7;

    const int r  = t >> 4;
    const int c4 = (t & 15) * 4;

    float4 s = *(const float4*)&scale[(size_t)g * NDIM + n0 + c4];

#pragma unroll
    for (int p = 0; p < 4; ++p) {
        const int kl = r + p * 16;
        int4 qv = *(const int4*)&q[(size_t)(k0 + kl) * NDIM + n0 + c4];
        lds[kl][c4 + 0] = f2h((float)(qv.x - 8) * s.x);
        lds[kl][c4 + 1] = f2h((float)(qv.y - 8) * s.y);
        lds[kl][c4 + 2] = f2h((float)(qv.z - 8) * s.z);
        lds[kl][c4 + 3] = f2h((float)(qv.w - 8) * s.w);
    }
    __syncthreads();

    const int kc = (t & 15) * 4;
#pragma unroll
    for (int p = 0; p < 4; ++p) {
        const int nl = (t >> 4) + p * 16;
        ushort4 o;
        o.x = lds[kc + 0][nl];
        o.y = lds[kc + 1][nl];
        o.z = lds[kc + 2][nl];
        o.w = lds[kc + 3][nl];
        *(ushort4*)&wt[(size_t)(n0 + nl) * KDIM + k0 + kc] = o;
    }
}

// ---------------- P2 fast: 128x256, BK=32, 2 blocks/CU ----------------
// LDS per buffer (halfs): A [128][32] at 0, B [256][32] at 4096; dbuf at 12288.
// Swizzle: LDS[row][ch] holds global[row][ch ^ ((row>>1)&3)] (16B chunk units);
// involution, read applies same XOR. Read banks: <=2-way (free, m136).
// Stage: 24 x 1KB issues/block/step = 3 per wave (A: issue w; B: issues 2w,2w+1).
// vmcnt: 3 loads/wave/tile; dbuf => steady in-flight 6, wait vmcnt(3).
__global__ __launch_bounds__(512, 4) void gemm_2b(const unsigned short* __restrict__ A,
                                                  const unsigned short* __restrict__ Bt,
                                                  float* __restrict__ C) {
    __shared__ unsigned short lds[2][12288];  // 48 KiB total

    const int t = threadIdx.x;
    const int w = t >> 6;   // wave 0..7
    const int l = t & 63;

    // XCD-aware bijective swizzle: 512 wgs, 8 XCDs, 64 contiguous per XCD.
    const int orig = blockIdx.x;
    const int wg = (orig & 7) * 64 + (orig >> 3);
    const int bx = wg & 15;   // N tile (256 wide)
    const int by = wg >> 4;   // M tile (128 tall)
    const int m0 = by * 128;
    const int n0 = bx * 256;

    const int wr = w >> 2;    // 0..1 : wave row (64 rows each)
    const int wc = w & 3;     // 0..3 : wave col (64 cols each)

    // ---- staging geometry (per-lane swizzled source; LDS dest linear) ----
    // issue covers 16 rows x 64B; lane l -> row_in_issue = l>>2, chunk = l&3;
    // source chunk = (l&3) ^ ((l>>3)&3)  [ = ch ^ ((row>>1)&3), row bit1..2 = l>>3 ]
    const int srow = l >> 2;                       // 0..15
    const int sc   = ((l & 3) ^ ((l >> 3) & 3)) * 8;  // swizzled source col (halfs)

    const unsigned short* pa  = A  + (size_t)(m0 + w * 16 + srow) * KDIM + sc;
    const unsigned short* pb0 = Bt + (size_t)(n0 + w * 32 + srow) * KDIM + sc;
    const unsigned short* pb1 = Bt + (size_t)(n0 + w * 32 + 16 + srow) * KDIM + sc;

    auto stage = [&](int buf, int kt) {
        const int kof = kt * 32;
        unsigned short* base = &lds[buf][0];
        __builtin_amdgcn_global_load_lds(
            (const __attribute__((address_space(1))) unsigned int*)(pa + kof),
            (__attribute__((address_space(3))) unsigned int*)(base + w * 512), 16, 0, 0);
        __builtin_amdgcn_global_load_lds(
            (const __attribute__((address_space(1))) unsigned int*)(pb0 + kof),
            (__attribute__((address_space(3))) unsigned int*)(base + 4096 + w * 1024), 16, 0, 0);
        __builtin_amdgcn_global_load_lds(
            (const __attribute__((address_space(1))) unsigned int*)(pb1 + kof),
            (__attribute__((address_space(3))) unsigned int*)(base + 4096 + w * 1024 + 512), 16, 0, 0);
    };

    // ---- fragment-read geometry ----
    const int lr = l & 15;    // frag row
    const int hi = l >> 4;    // 0..3 : k chunk (8 halfs)
    const int ca = (hi ^ ((lr >> 1) & 3)) * 8;  // phys chunk offset (halfs)
    const int arow = wr * 64 + lr;
    const int brow = wc * 64 + lr;

    f32x4 acc[4][4];
#pragma unroll
    for (int mi = 0; mi < 4; ++mi)
#pragma unroll
        for (int ni = 0; ni < 4; ++ni)
            acc[mi][ni] = (f32x4){0.f, 0.f, 0.f, 0.f};

    stage(0, 0);
    stage(1, 1);

    const int NT = KDIM / 32;  // 128
    for (int kt = 0; kt < NT; ++kt) {
        if (kt == NT - 1)
            asm volatile("s_waitcnt vmcnt(0)" ::: "memory");
        else
            asm volatile("s_waitcnt vmcnt(3)" ::: "memory");  // my tile-kt loads landed
        __builtin_amdgcn_s_barrier();                          // block-wide ready

        const int bsel = kt & 1;
        const unsigned short* sA = &lds[bsel][0];
        const unsigned short* sB = &lds[bsel][4096];

        f16x8 a[4], b[4];
#pragma unroll
        for (int mi = 0; mi < 4; ++mi)
            a[mi] = *(const f16x8*)&sA[(arow + mi * 16) * 32 + ca];
#pragma unroll
        for (int ni = 0; ni < 4; ++ni)
            b[ni] = *(const f16x8*)&sB[(brow + ni * 16) * 32 + ca];

        __builtin_amdgcn_s_setprio(1);
#pragma unroll
        for (int mi = 0; mi < 4; ++mi)
#pragma unroll
            for (int ni = 0; ni < 4; ++ni)
                acc[mi][ni] = __builtin_amdgcn_mfma_f32_16x16x32_f16(
                    a[mi], b[ni], acc[mi][ni], 0, 0, 0);
        __builtin_amdgcn_s_setprio(0);

        __builtin_amdgcn_s_barrier();          // all waves done reading buf bsel
        if (kt + 2 < NT) stage(bsel, kt + 2);  // overwrite freed buf; awaited kt+2
    }

    // epilogue: D layout col = lane&15, row = (lane>>4)*4 + reg
#pragma unroll
    for (int mi = 0; mi < 4; ++mi) {
#pragma unroll
        for (int ni = 0; ni < 4; ++ni) {
            const int row = m0 + wr * 64 + mi * 16 + hi * 4;
            const int col = n0 + wc * 64 + ni * 16 + lr;
#pragma unroll
            for (int r2 = 0; r2 < 4; ++r2)
                C[(size_t)(row + r2) * NDIM + col] = acc[mi][ni][r2];
        }
    }
}

// ---------------- P2 fallback: round-3 reg-staged GEMM (proven) ----------------
__global__ __launch_bounds__(256) void gemm_bt(const float* __restrict__ A,
                                               const unsigned short* __restrict__ Bt,
                                               float* __restrict__ C) {
    __shared__ unsigned short sA[2][128 * 32];
    __shared__ unsigned short sB[2][128 * 32];

    const int t = threadIdx.x;
    const int l = t & 63;
    const int w = t >> 6;

    const int m0 = blockIdx.y * 128;
    const int n0 = blockIdx.x * 128;

    const float*          Arow = A  + (size_t)m0 * KDIM;
    const unsigned short* Brow = Bt + (size_t)n0 * KDIM;

    const int r0 = t >> 2;
    const int c0 = (t & 3) * 8;

    float4 fa[4];
    i32x4  pb0, pb1;
    auto gload = [&](int kt) {
        const size_t oa0 = (size_t)r0 * KDIM + (size_t)kt * 32 + c0;
        const size_t oa1 = (size_t)(r0 + 64) * KDIM + (size_t)kt * 32 + c0;
        fa[0] = *(const float4*)(Arow + oa0);
        fa[1] = *(const float4*)(Arow + oa0 + 4);
        fa[2] = *(const float4*)(Arow + oa1);
        fa[3] = *(const float4*)(Arow + oa1 + 4);
        pb0 = *(const i32x4*)(Brow + oa0);
        pb1 = *(const i32x4*)(Brow + oa1);
    };
    auto pack8 = [&](float4 a, float4 b) {
        f16x8 r;
        r[0] = (_Float16)a.x; r[1] = (_Float16)a.y;
        r[2] = (_Float16)a.z; r[3] = (_Float16)a.w;
        r[4] = (_Float16)b.x; r[5] = (_Float16)b.y;
        r[6] = (_Float16)b.z; r[7] = (_Float16)b.w;
        return r;
    };
    auto swrite = [&](int buf) {
        *(f16x8*)&sA[buf][r0 * 32 + c0]        = pack8(fa[0], fa[1]);
        *(f16x8*)&sA[buf][(r0 + 64) * 32 + c0] = pack8(fa[2], fa[3]);
        *(i32x4*)&sB[buf][r0 * 32 + c0]        = pb0;
        *(i32x4*)&sB[buf][(r0 + 64) * 32 + c0] = pb1;
    };

    f32x4 acc[4][4];
#pragma unroll
    for (int mi = 0; mi < 4; ++mi)
#pragma unroll
        for (int ni = 0; ni < 4; ++ni)
            acc[mi][ni] = (f32x4){0.f, 0.f, 0.f, 0.f};

    const int wm = (w >> 1) * 64;
    const int wn = (w & 1) * 64;
    const int lr = l & 15;
    const int lk = (l >> 4) * 8;

    gload(0);
    swrite(0);

    const int NT = KDIM / 32;
    for (int kt = 0; kt < NT; ++kt) {
        const int cur = kt & 1;
        __syncthreads();
        if (kt + 1 < NT) gload(kt + 1);

        f16x8 a[4], b[4];
#pragma unroll
        for (int mi = 0; mi < 4; ++mi)
            a[mi] = *(const f16x8*)&sA[cur][(wm + mi * 16 + lr) * 32 + lk];
#pragma unroll
        for (int ni = 0; ni < 4; ++ni)
            b[ni] = *(const f16x8*)&sB[cur][(wn + ni * 16 + lr) * 32 + lk];

#pragma unroll
        for (int mi = 0; mi < 4; ++mi)
#pragma unroll
            for (int ni = 0; ni < 4; ++ni)
                acc[mi][ni] = __builtin_amdgcn_mfma_f32_16x16x32_f16(
                    a[mi], b[ni], acc[mi][ni], 0, 0, 0);

        if (kt + 1 < NT) swrite(cur ^ 1);
    }

#pragma unroll
    for (int mi = 0; mi < 4; ++mi) {
#pragma unroll
        for (int ni = 0; ni < 4; ++ni) {
            const int row = m0 + wm + mi * 16 + (l >> 4) * 4;
            const int col = n0 + wn + ni * 16 + lr;
#pragma unroll
            for (int r2 = 0; r2 < 4; ++r2)
                C[(size_t)(row + r2) * NDIM + col] = acc[mi][ni][r2];
        }
    }
}

extern "C" void kernel_launch(void* const* d_in, const int* in_sizes, int n_in,
                              void* d_out, int out_size, void* d_ws, size_t ws_size,
                              hipStream_t stream) {
    const float* x     = (const float*)d_in[0];
    const float* scale = (const float*)d_in[1];
    const int*   qw    = (const int*)d_in[2];
    float*       out   = (float*)d_out;

    const size_t wtBytes = (size_t)NDIM * KDIM * 2;  // 32 MB
    const size_t xhBytes = (size_t)MDIM * KDIM * 2;  // 32 MB

    if (ws_size >= wtBytes + xhBytes) {
        unsigned short* wt = (unsigned short*)d_ws;
        unsigned short* xh = (unsigned short*)((char*)d_ws + wtBytes);
        convert_x<<<2048, 256, 0, stream>>>(x, xh, MDIM * KDIM / 8);
        dequant_transpose<<<dim3(KDIM / 64, NDIM / 64), 256, 0, stream>>>(qw, scale, wt);
        gemm_2b<<<dim3(512), 512, 0, stream>>>(xh, wt, out);
    } else if (ws_size >= wtBytes) {
        unsigned short* wt = (unsigned short*)d_ws;
        dequant_transpose<<<dim3(KDIM / 64, NDIM / 64), 256, 0, stream>>>(qw, scale, wt);
        gemm_bt<<<dim3(NDIM / 128, MDIM / 128), 256, 0, stream>>>(x, wt, out);
    } else {
        zero_fill<<<(out_size + 255) / 256, 256, 0, stream>>>(out, out_size);
    }
}